// Round 2
// baseline (894.355 us; speedup 1.0000x reference)
//
#include <hip/hip_runtime.h>

#define SEQ 2048
#define HID 1024
#define NH 16
#define DH 64
#define BTCH 2
#define SCALE 0.125f
#define SCALING 2.0f

typedef __bf16 bf16;
typedef __attribute__((ext_vector_type(8))) __bf16 bf16x8;
typedef __attribute__((ext_vector_type(4))) float f32x4;

__device__ __forceinline__ f32x4 zero4() {
    f32x4 z; z[0] = 0.f; z[1] = 0.f; z[2] = 0.f; z[3] = 0.f; return z;
}

// ---------------------------------------------------------------------------
// Kernel 1: fold LoRA into effective weight (fp32 in, bf16 out):
//   Weff[o,h] = W[o,h] + 2*sum_r B[o,r]*A[r,h]
// grid: (1024*1024/256, 3)
// ---------------------------------------------------------------------------
__global__ __launch_bounds__(256) void weff_kernel(
    const float* __restrict__ Wq, const float* __restrict__ Aq, const float* __restrict__ Bq,
    const float* __restrict__ Wk, const float* __restrict__ Ak, const float* __restrict__ Bk,
    const float* __restrict__ Wv, const float* __restrict__ Av, const float* __restrict__ Bv,
    bf16* __restrict__ weff)
{
    const int p = blockIdx.y;
    const float* W = (p == 0) ? Wq : (p == 1) ? Wk : Wv;
    const float* A = (p == 0) ? Aq : (p == 1) ? Ak : Av;
    const float* B = (p == 0) ? Bq : (p == 1) ? Bk : Bv;
    const int e = blockIdx.x * 256 + threadIdx.x;   // e in [0, 1024*1024)
    const int o = e >> 10;
    const int hc = e & 1023;
    float acc = W[e];
#pragma unroll
    for (int r = 0; r < 8; ++r)
        acc += SCALING * B[o * 8 + r] * A[r * 1024 + hc];
    weff[(size_t)p * 1024 * 1024 + e] = (bf16)acc;
}

// ---------------------------------------------------------------------------
// Kernel 2: Y = X @ Weff^T + bias   (X fp32 [4096,1024], Weff bf16 [out,in])
// 64x64 output tile per block, 4 waves, BK=64, mfma_f32_16x16x32_bf16.
// X converted fp32->bf16 during LDS staging. Output Y is bf16 (ws).
// grid: (16 n-tiles, 64 m-tiles, 3 projections), block 256
// ---------------------------------------------------------------------------
__global__ __launch_bounds__(256) void proj_kernel(
    const float* __restrict__ xq, const float* __restrict__ xk, const float* __restrict__ xv,
    const float* __restrict__ bq, const float* __restrict__ bk, const float* __restrict__ bv,
    const bf16* __restrict__ weff, bf16* __restrict__ qkvh)
{
    __shared__ bf16 Xs[64 * 72];   // rows padded to 72 (144 B)
    __shared__ bf16 Ws[64 * 72];

    const int p = blockIdx.z;
    const float* X    = (p == 0) ? xq : (p == 1) ? xk : xv;
    const float* bias = (p == 0) ? bq : (p == 1) ? bk : bv;
    const bf16* W = weff + (size_t)p * HID * HID;
    bf16* Y = qkvh + (size_t)p * BTCH * SEQ * HID;

    const int tid = threadIdx.x;
    const int wave = tid >> 6;
    const int lane = tid & 63;
    const int g = lane >> 4;       // k-group for A/B frags, row-group for C
    const int lm = lane & 15;      // m (A) / n (B) / col (C)
    const int m0 = blockIdx.y * 64;
    const int n0 = blockIdx.x * 64;

    f32x4 acc[4];
#pragma unroll
    for (int c = 0; c < 4; ++c) acc[c] = zero4();

    for (int k0 = 0; k0 < HID; k0 += 64) {
#pragma unroll
        for (int i = 0; i < 2; ++i) {
            const int c = tid + i * 256;
            const int row = c >> 3;
            const int cv = c & 7;
            // X: 8 fp32 -> bf16x8
            const float* xsrc = &X[(size_t)(m0 + row) * HID + k0 + cv * 8];
            f32x4 x0 = *(const f32x4*)(xsrc);
            f32x4 x1 = *(const f32x4*)(xsrc + 4);
            bf16x8 xb;
#pragma unroll
            for (int j = 0; j < 4; ++j) { xb[j] = (bf16)x0[j]; xb[4 + j] = (bf16)x1[j]; }
            *(bf16x8*)&Xs[row * 72 + cv * 8] = xb;
            // W: already bf16
            *(bf16x8*)&Ws[row * 72 + cv * 8] =
                *(const bf16x8*)&W[(size_t)(n0 + row) * HID + k0 + cv * 8];
        }
        __syncthreads();
#pragma unroll
        for (int s = 0; s < 2; ++s) {
            bf16x8 a = *(const bf16x8*)&Xs[(wave * 16 + lm) * 72 + s * 32 + g * 8];
#pragma unroll
            for (int c = 0; c < 4; ++c) {
                bf16x8 bb = *(const bf16x8*)&Ws[(c * 16 + lm) * 72 + s * 32 + g * 8];
                acc[c] = __builtin_amdgcn_mfma_f32_16x16x32_bf16(a, bb, acc[c], 0, 0, 0);
            }
        }
        __syncthreads();
    }

    // epilogue: +bias, write bf16. C layout: col = lm, row = g*4 + r
#pragma unroll
    for (int c = 0; c < 4; ++c) {
        const float bv_ = bias[n0 + c * 16 + lm];
#pragma unroll
        for (int r = 0; r < 4; ++r) {
            const int row = m0 + wave * 16 + g * 4 + r;
            Y[(size_t)row * HID + n0 + c * 16 + lm] = (bf16)(acc[c][r] + bv_);
        }
    }
}

// ---------------------------------------------------------------------------
// Kernel 3: flash attention. One block = one (b, h, 64-row Q tile). 4 waves,
// each wave owns 16 Q rows end-to-end. BN=64 K/V tiles, online softmax.
// q/k/v bf16 from ws; attn_bias fp32; output fp32.
// grid: (32, 16, 2), block 256
// ---------------------------------------------------------------------------
__global__ __launch_bounds__(256) void attn_kernel(
    const bf16* __restrict__ qkvh, const float* __restrict__ attn_bias,
    float* __restrict__ out)
{
    __shared__ bf16 Ks[64 * 72];   // K tile row-major [kk][d]
    __shared__ bf16 Vt[64 * 72];   // V tile transposed [d][kk]
    __shared__ bf16 Ps[64 * 72];   // P tile row-major [q][kk]

    const int tid = threadIdx.x;
    const int wave = tid >> 6;
    const int lane = tid & 63;
    const int g = lane >> 4;
    const int lm = lane & 15;

    const int q0 = blockIdx.x * 64;
    const int h = blockIdx.y;
    const int b = blockIdx.z;

    const bf16* qh = qkvh;
    const bf16* kh = qkvh + (size_t)BTCH * SEQ * HID;
    const bf16* vh = qkvh + (size_t)2 * BTCH * SEQ * HID;

    // Q A-fragment: rows q0+wave*16+lm, d = s*32 + g*8 + j  — loaded once
    const bf16* qrow = qh + (size_t)(b * SEQ + q0 + wave * 16 + lm) * HID + h * DH;
    bf16x8 qf0 = *(const bf16x8*)(qrow + g * 8);
    bf16x8 qf1 = *(const bf16x8*)(qrow + 32 + g * 8);

    f32x4 acc_o[4];
    float m2[4], l[4];
#pragma unroll
    for (int c = 0; c < 4; ++c) acc_o[c] = zero4();
#pragma unroll
    for (int r = 0; r < 4; ++r) { m2[r] = -__builtin_inff(); l[r] = 0.f; }

    const size_t bias_base = (size_t)(b * NH + h) * SEQ * SEQ;

    for (int kv0 = 0; kv0 < SEQ; kv0 += 64) {
        // stage K (row-major) and V (transposed) tiles from bf16 ws
#pragma unroll
        for (int i = 0; i < 2; ++i) {
            const int c = tid + i * 256;
            const int row = c >> 3;    // kk within tile
            const int cv = c & 7;      // d-group of 8
            const size_t src = (size_t)(b * SEQ + kv0 + row) * HID + h * DH + cv * 8;
            *(bf16x8*)&Ks[row * 72 + cv * 8] = *(const bf16x8*)&kh[src];
            bf16x8 vv = *(const bf16x8*)&vh[src];
#pragma unroll
            for (int j = 0; j < 8; ++j)
                Vt[(cv * 8 + j) * 72 + row] = vv[j];
        }
        __syncthreads();

        // S = Q K^T : wave computes 16 rows x 64 cols
        f32x4 sacc[4];
#pragma unroll
        for (int c = 0; c < 4; ++c) sacc[c] = zero4();
#pragma unroll
        for (int s = 0; s < 2; ++s) {
            bf16x8 a = (s == 0) ? qf0 : qf1;
#pragma unroll
            for (int c = 0; c < 4; ++c) {
                bf16x8 bb = *(const bf16x8*)&Ks[(c * 16 + lm) * 72 + s * 32 + g * 8];
                sacc[c] = __builtin_amdgcn_mfma_f32_16x16x32_bf16(a, bb, sacc[c], 0, 0, 0);
            }
        }

        // t = S*SCALE + bias   (C layout: row = g*4+r, col = c*16+lm)
        float t[4][4];
#pragma unroll
        for (int c = 0; c < 4; ++c) {
#pragma unroll
            for (int r = 0; r < 4; ++r) {
                const int qq = q0 + wave * 16 + g * 4 + r;
                const int kk = kv0 + c * 16 + lm;
                const float bval = attn_bias[bias_base + (size_t)qq * SEQ + kk];
                t[c][r] = sacc[c][r] * SCALE + bval;
            }
        }

        // online softmax: reduce across the 16 lanes of each row group
        float rmax[4];
#pragma unroll
        for (int r = 0; r < 4; ++r)
            rmax[r] = fmaxf(fmaxf(t[0][r], t[1][r]), fmaxf(t[2][r], t[3][r]));
#pragma unroll
        for (int off = 1; off < 16; off <<= 1) {
#pragma unroll
            for (int r = 0; r < 4; ++r)
                rmax[r] = fmaxf(rmax[r], __shfl_xor(rmax[r], off));
        }

        float alpha[4];
#pragma unroll
        for (int r = 0; r < 4; ++r) {
            const float mn = fmaxf(m2[r], rmax[r]);
            alpha[r] = __expf(m2[r] - mn);   // exp(-inf)=0 on first tile
            m2[r] = mn;
        }

        float rsum[4] = {0.f, 0.f, 0.f, 0.f};
#pragma unroll
        for (int c = 0; c < 4; ++c) {
#pragma unroll
            for (int r = 0; r < 4; ++r) {
                const float pv = __expf(t[c][r] - m2[r]);
                rsum[r] += pv;
                Ps[(wave * 16 + g * 4 + r) * 72 + c * 16 + lm] = (bf16)pv;
            }
        }
#pragma unroll
        for (int off = 1; off < 16; off <<= 1) {
#pragma unroll
            for (int r = 0; r < 4; ++r)
                rsum[r] += __shfl_xor(rsum[r], off);
        }
#pragma unroll
        for (int r = 0; r < 4; ++r)
            l[r] = l[r] * alpha[r] + rsum[r];
#pragma unroll
        for (int c = 0; c < 4; ++c) {
#pragma unroll
            for (int r = 0; r < 4; ++r)
                acc_o[c][r] *= alpha[r];
        }

        __syncthreads();   // Ps visible (and safely ordered) before A-frag read

        // O += P @ V
#pragma unroll
        for (int s = 0; s < 2; ++s) {
            bf16x8 pa = *(const bf16x8*)&Ps[(wave * 16 + lm) * 72 + s * 32 + g * 8];
#pragma unroll
            for (int c = 0; c < 4; ++c) {
                bf16x8 vb = *(const bf16x8*)&Vt[(c * 16 + lm) * 72 + s * 32 + g * 8];
                acc_o[c] = __builtin_amdgcn_mfma_f32_16x16x32_bf16(pa, vb, acc_o[c], 0, 0, 0);
            }
        }
        __syncthreads();   // protect Ks/Vt/Ps before next tile's staging
    }

    // epilogue: O / l, write fp32 [b][q][h*64+d]
#pragma unroll
    for (int c = 0; c < 4; ++c) {
#pragma unroll
        for (int r = 0; r < 4; ++r) {
            const int qq = q0 + wave * 16 + g * 4 + r;
            out[(size_t)(b * SEQ + qq) * HID + h * DH + c * 16 + lm] =
                acc_o[c][r] / l[r];
        }
    }
}

// ---------------------------------------------------------------------------
extern "C" void kernel_launch(void* const* d_in, const int* in_sizes, int n_in,
                              void* d_out, int out_size, void* d_ws, size_t ws_size,
                              hipStream_t stream)
{
    const float* q  = (const float*)d_in[0];
    const float* k  = (const float*)d_in[1];
    const float* v  = (const float*)d_in[2];
    const float* ab = (const float*)d_in[3];
    const float* Wq = (const float*)d_in[4];
    const float* bq = (const float*)d_in[5];
    const float* Aq = (const float*)d_in[6];
    const float* Bq = (const float*)d_in[7];
    const float* Wk = (const float*)d_in[8];
    const float* bk = (const float*)d_in[9];
    const float* Ak = (const float*)d_in[10];
    const float* Bk = (const float*)d_in[11];
    const float* Wv = (const float*)d_in[12];
    const float* bv = (const float*)d_in[13];
    const float* Av = (const float*)d_in[14];
    const float* Bv = (const float*)d_in[15];

    bf16* weff = (bf16*)d_ws;                       // 3 * 1024*1024 bf16 = 6 MB
    bf16* qkvh = weff + (size_t)3 * 1024 * 1024;    // 3 * 4096*1024 bf16 = 24 MB

    weff_kernel<<<dim3(1024 * 1024 / 256, 3), 256, 0, stream>>>(
        Wq, Aq, Bq, Wk, Ak, Bk, Wv, Av, Bv, weff);

    proj_kernel<<<dim3(HID / 64, BTCH * SEQ / 64, 3), 256, 0, stream>>>(
        q, k, v, bq, bk, bv, weff, qkvh);

    attn_kernel<<<dim3(SEQ / 64, NH, BTCH), 256, 0, stream>>>(
        qkvh, ab, (float*)d_out);
}

// Round 3
// 849.285 us; speedup vs baseline: 1.0531x; 1.0531x over previous
//
#include <hip/hip_runtime.h>

#define SEQ 2048
#define HID 1024
#define NH 16
#define DH 64
#define BTCH 2
#define SCALE 0.125f
#define SCALING 2.0f
#define LOG2E 1.4426950408889634f

typedef __bf16 bf16;
typedef __attribute__((ext_vector_type(8))) __bf16 bf16x8;
typedef __attribute__((ext_vector_type(4))) float f32x4;

__device__ __forceinline__ f32x4 zero4() {
    f32x4 z; z[0] = 0.f; z[1] = 0.f; z[2] = 0.f; z[3] = 0.f; return z;
}

// ---------------------------------------------------------------------------
// Kernel 1a: fold LoRA into effective weight (fp32 in, bf16 out)
// grid: (4096, 3), block 256
// ---------------------------------------------------------------------------
__global__ __launch_bounds__(256) void weff_kernel(
    const float* __restrict__ Wq, const float* __restrict__ Aq, const float* __restrict__ Bq,
    const float* __restrict__ Wk, const float* __restrict__ Ak, const float* __restrict__ Bk,
    const float* __restrict__ Wv, const float* __restrict__ Av, const float* __restrict__ Bv,
    bf16* __restrict__ weff)
{
    const int p = blockIdx.y;
    const float* W = (p == 0) ? Wq : (p == 1) ? Wk : Wv;
    const float* A = (p == 0) ? Aq : (p == 1) ? Ak : Av;
    const float* B = (p == 0) ? Bq : (p == 1) ? Bk : Bv;
    const int e = blockIdx.x * 256 + threadIdx.x;
    const int o = e >> 10;
    const int hc = e & 1023;
    float acc = W[e];
#pragma unroll
    for (int r = 0; r < 8; ++r)
        acc += SCALING * B[o * 8 + r] * A[r * 1024 + hc];
    weff[(size_t)p * 1024 * 1024 + e] = (bf16)acc;
}

// ---------------------------------------------------------------------------
// Kernel 1b: cast q,k,v fp32 -> bf16 (8 elems/thread)
// grid: (2048, 3), block 256
// ---------------------------------------------------------------------------
__global__ __launch_bounds__(256) void cast_kernel(
    const float* __restrict__ xq, const float* __restrict__ xk, const float* __restrict__ xv,
    bf16* __restrict__ xb)
{
    const int p = blockIdx.y;
    const float* X = (p == 0) ? xq : (p == 1) ? xk : xv;
    const size_t e = ((size_t)blockIdx.x * 256 + threadIdx.x) * 8;
    f32x4 x0 = *(const f32x4*)(X + e);
    f32x4 x1 = *(const f32x4*)(X + e + 4);
    bf16x8 xo;
#pragma unroll
    for (int j = 0; j < 4; ++j) { xo[j] = (bf16)x0[j]; xo[4 + j] = (bf16)x1[j]; }
    *(bf16x8*)&xb[(size_t)p * BTCH * SEQ * HID + e] = xo;
}

// ---------------------------------------------------------------------------
// Kernel 2: Y = X @ Weff^T + bias  (pure bf16 MFMA, 128x128 tile, 4 waves)
// p==0 (Q) output pre-scaled by SCALE*LOG2E for the exp2 softmax path.
// grid: (8 n-tiles, 32 m-tiles, 3), block 256
// ---------------------------------------------------------------------------
__global__ __launch_bounds__(256) void proj_kernel(
    const bf16* __restrict__ xb,
    const float* __restrict__ bq, const float* __restrict__ bk, const float* __restrict__ bv,
    const bf16* __restrict__ weff, bf16* __restrict__ qkvh)
{
    __shared__ bf16 Xs[128 * 72];
    __shared__ bf16 Ws[128 * 72];

    const int p = blockIdx.z;
    const bf16* X = xb + (size_t)p * BTCH * SEQ * HID;
    const float* bias = (p == 0) ? bq : (p == 1) ? bk : bv;
    const bf16* W = weff + (size_t)p * HID * HID;
    bf16* Y = qkvh + (size_t)p * BTCH * SEQ * HID;

    const int tid = threadIdx.x;
    const int wave = tid >> 6;
    const int lane = tid & 63;
    const int g = lane >> 4;
    const int lm = lane & 15;
    const int wm = (wave >> 1) * 64;   // wave row offset in tile
    const int wn = (wave & 1) * 64;    // wave col offset in tile
    const int m0 = blockIdx.y * 128;
    const int n0 = blockIdx.x * 128;

    f32x4 acc[4][4];
#pragma unroll
    for (int mi = 0; mi < 4; ++mi)
#pragma unroll
        for (int ni = 0; ni < 4; ++ni) acc[mi][ni] = zero4();

    for (int k0 = 0; k0 < HID; k0 += 64) {
#pragma unroll
        for (int i = 0; i < 4; ++i) {
            const int idx = tid + i * 256;     // 0..1023
            const int row = idx >> 3;
            const int ch = idx & 7;
            *(bf16x8*)&Xs[row * 72 + ch * 8] =
                *(const bf16x8*)&X[(size_t)(m0 + row) * HID + k0 + ch * 8];
            *(bf16x8*)&Ws[row * 72 + ch * 8] =
                *(const bf16x8*)&W[(size_t)(n0 + row) * HID + k0 + ch * 8];
        }
        __syncthreads();
#pragma unroll
        for (int s = 0; s < 2; ++s) {
            bf16x8 a[4], b[4];
#pragma unroll
            for (int mi = 0; mi < 4; ++mi)
                a[mi] = *(const bf16x8*)&Xs[(wm + mi * 16 + lm) * 72 + s * 32 + g * 8];
#pragma unroll
            for (int ni = 0; ni < 4; ++ni)
                b[ni] = *(const bf16x8*)&Ws[(wn + ni * 16 + lm) * 72 + s * 32 + g * 8];
#pragma unroll
            for (int mi = 0; mi < 4; ++mi)
#pragma unroll
                for (int ni = 0; ni < 4; ++ni)
                    acc[mi][ni] = __builtin_amdgcn_mfma_f32_16x16x32_bf16(
                        a[mi], b[ni], acc[mi][ni], 0, 0, 0);
        }
        __syncthreads();
    }

    const float oscale = (p == 0) ? (SCALE * LOG2E) : 1.0f;
#pragma unroll
    for (int ni = 0; ni < 4; ++ni) {
        const float bv_ = bias[n0 + wn + ni * 16 + lm];
#pragma unroll
        for (int mi = 0; mi < 4; ++mi) {
#pragma unroll
            for (int r = 0; r < 4; ++r) {
                const int row = m0 + wm + mi * 16 + g * 4 + r;
                Y[(size_t)row * HID + n0 + wn + ni * 16 + lm] =
                    (bf16)((acc[mi][ni][r] + bv_) * oscale);
            }
        }
    }
}

// ---------------------------------------------------------------------------
// Kernel 3: transpose V: vh[b][s][c] -> vt[b][c][s]   (c = h*64+d)
// grid: (32 s-tiles, 16 c-tiles, 2), block 256, 64x64 tiles
// ---------------------------------------------------------------------------
__global__ __launch_bounds__(256) void vtrans_kernel(
    const bf16* __restrict__ vh, bf16* __restrict__ vt)
{
    __shared__ bf16 T[64 * 76];   // pad 76: read phase conflict-free, write ~2-way
    const int tid = threadIdx.x;
    const int s0 = blockIdx.x * 64;
    const int c0 = blockIdx.y * 64;
    const int b = blockIdx.z;

#pragma unroll
    for (int i = 0; i < 2; ++i) {
        const int idx = tid + i * 256;
        const int row = idx >> 3;      // s within tile
        const int ch = idx & 7;
        *(bf16x8*)&T[row * 76 + ch * 8] =
            *(const bf16x8*)&vh[(size_t)(b * SEQ + s0 + row) * HID + c0 + ch * 8];
    }
    __syncthreads();
#pragma unroll
    for (int i = 0; i < 2; ++i) {
        const int idx = tid + i * 256;
        const int row = idx >> 3;      // c within tile
        const int ch = idx & 7;        // s-chunk
        bf16x8 o;
#pragma unroll
        for (int u = 0; u < 8; ++u)
            o[u] = T[(ch * 8 + u) * 76 + row];
        *(bf16x8*)&vt[((size_t)b * HID + c0 + row) * SEQ + s0 + ch * 8] = o;
    }
}

// ---------------------------------------------------------------------------
// Kernel 4: flash attention. One block = (b, h, 64-row Q tile), 4 waves.
// Q pre-scaled by SCALE*log2e -> exp2 softmax. V from pre-transposed vt.
// grid: (32, 16, 2), block 256
// ---------------------------------------------------------------------------
__global__ __launch_bounds__(256) void attn_kernel(
    const bf16* __restrict__ qkvh, const bf16* __restrict__ vt,
    const float* __restrict__ attn_bias, float* __restrict__ out)
{
    __shared__ bf16 Ks[64 * 72];   // K tile row-major [kk][d]
    __shared__ bf16 Vt[64 * 72];   // V tile transposed [d][kk]
    __shared__ bf16 Ps[64 * 72];   // P tile row-major [q][kk]

    const int tid = threadIdx.x;
    const int wave = tid >> 6;
    const int lane = tid & 63;
    const int g = lane >> 4;
    const int lm = lane & 15;

    const int q0 = blockIdx.x * 64;
    const int h = blockIdx.y;
    const int b = blockIdx.z;

    const bf16* qh = qkvh;
    const bf16* kh = qkvh + (size_t)BTCH * SEQ * HID;

    const bf16* qrow = qh + (size_t)(b * SEQ + q0 + wave * 16 + lm) * HID + h * DH;
    bf16x8 qf0 = *(const bf16x8*)(qrow + g * 8);
    bf16x8 qf1 = *(const bf16x8*)(qrow + 32 + g * 8);

    f32x4 acc_o[4];
    float m2[4], l[4];
#pragma unroll
    for (int c = 0; c < 4; ++c) acc_o[c] = zero4();
#pragma unroll
    for (int r = 0; r < 4; ++r) { m2[r] = -__builtin_inff(); l[r] = 0.f; }

    const size_t bias_base = (size_t)(b * NH + h) * SEQ * SEQ;

    for (int kv0 = 0; kv0 < SEQ; kv0 += 64) {
        // stage K (row-major) and Vt (already d-major) — both vectorized
#pragma unroll
        for (int i = 0; i < 2; ++i) {
            const int idx = tid + i * 256;
            const int row = idx >> 3;
            const int ch = idx & 7;
            *(bf16x8*)&Ks[row * 72 + ch * 8] =
                *(const bf16x8*)&kh[(size_t)(b * SEQ + kv0 + row) * HID + h * DH + ch * 8];
            *(bf16x8*)&Vt[row * 72 + ch * 8] =
                *(const bf16x8*)&vt[((size_t)b * HID + h * DH + row) * SEQ + kv0 + ch * 8];
        }
        __syncthreads();

        // S' = Qs K^T   (Qs already has SCALE*log2e folded in)
        f32x4 sacc[4];
#pragma unroll
        for (int c = 0; c < 4; ++c) sacc[c] = zero4();
#pragma unroll
        for (int s = 0; s < 2; ++s) {
            bf16x8 a = (s == 0) ? qf0 : qf1;
#pragma unroll
            for (int c = 0; c < 4; ++c) {
                bf16x8 bb = *(const bf16x8*)&Ks[(c * 16 + lm) * 72 + s * 32 + g * 8];
                sacc[c] = __builtin_amdgcn_mfma_f32_16x16x32_bf16(a, bb, sacc[c], 0, 0, 0);
            }
        }

        // t = S' + bias*log2e   (exp2 domain). C layout: row=g*4+r, col=c*16+lm
        float t[4][4];
#pragma unroll
        for (int c = 0; c < 4; ++c) {
#pragma unroll
            for (int r = 0; r < 4; ++r) {
                const int qq = q0 + wave * 16 + g * 4 + r;
                const int kk = kv0 + c * 16 + lm;
                const float bval = attn_bias[bias_base + (size_t)qq * SEQ + kk];
                t[c][r] = __builtin_fmaf(bval, LOG2E, sacc[c][r]);
            }
        }

        // online softmax (base-2)
        float rmax[4];
#pragma unroll
        for (int r = 0; r < 4; ++r)
            rmax[r] = fmaxf(fmaxf(t[0][r], t[1][r]), fmaxf(t[2][r], t[3][r]));
#pragma unroll
        for (int off = 1; off < 16; off <<= 1) {
#pragma unroll
            for (int r = 0; r < 4; ++r)
                rmax[r] = fmaxf(rmax[r], __shfl_xor(rmax[r], off));
        }

        float alpha[4];
#pragma unroll
        for (int r = 0; r < 4; ++r) {
            const float mn = fmaxf(m2[r], rmax[r]);
            alpha[r] = exp2f(m2[r] - mn);   // exp2(-inf)=0 on first tile
            m2[r] = mn;
        }

        float rsum[4] = {0.f, 0.f, 0.f, 0.f};
#pragma unroll
        for (int c = 0; c < 4; ++c) {
#pragma unroll
            for (int r = 0; r < 4; ++r) {
                const float pv = exp2f(t[c][r] - m2[r]);
                rsum[r] += pv;
                Ps[(wave * 16 + g * 4 + r) * 72 + c * 16 + lm] = (bf16)pv;
            }
        }
#pragma unroll
        for (int off = 1; off < 16; off <<= 1) {
#pragma unroll
            for (int r = 0; r < 4; ++r)
                rsum[r] += __shfl_xor(rsum[r], off);
        }
#pragma unroll
        for (int r = 0; r < 4; ++r)
            l[r] = l[r] * alpha[r] + rsum[r];
#pragma unroll
        for (int c = 0; c < 4; ++c) {
#pragma unroll
            for (int r = 0; r < 4; ++r)
                acc_o[c][r] *= alpha[r];
        }

        __syncthreads();   // Ps ordering + all waves done with this tile's S

        // O += P @ V
#pragma unroll
        for (int s = 0; s < 2; ++s) {
            bf16x8 pa = *(const bf16x8*)&Ps[(wave * 16 + lm) * 72 + s * 32 + g * 8];
#pragma unroll
            for (int c = 0; c < 4; ++c) {
                bf16x8 vb = *(const bf16x8*)&Vt[(c * 16 + lm) * 72 + s * 32 + g * 8];
                acc_o[c] = __builtin_amdgcn_mfma_f32_16x16x32_bf16(pa, vb, acc_o[c], 0, 0, 0);
            }
        }
        __syncthreads();   // protect Ks/Vt/Ps before next staging
    }

    // epilogue: O / l, fp32 out [b][q][h*64+d]
#pragma unroll
    for (int c = 0; c < 4; ++c) {
#pragma unroll
        for (int r = 0; r < 4; ++r) {
            const int qq = q0 + wave * 16 + g * 4 + r;
            out[(size_t)(b * SEQ + qq) * HID + h * DH + c * 16 + lm] =
                acc_o[c][r] / l[r];
        }
    }
}

// ---------------------------------------------------------------------------
extern "C" void kernel_launch(void* const* d_in, const int* in_sizes, int n_in,
                              void* d_out, int out_size, void* d_ws, size_t ws_size,
                              hipStream_t stream)
{
    const float* q  = (const float*)d_in[0];
    const float* k  = (const float*)d_in[1];
    const float* v  = (const float*)d_in[2];
    const float* ab = (const float*)d_in[3];
    const float* Wq = (const float*)d_in[4];
    const float* bq = (const float*)d_in[5];
    const float* Aq = (const float*)d_in[6];
    const float* Bq = (const float*)d_in[7];
    const float* Wk = (const float*)d_in[8];
    const float* bk = (const float*)d_in[9];
    const float* Ak = (const float*)d_in[10];
    const float* Bk = (const float*)d_in[11];
    const float* Wv = (const float*)d_in[12];
    const float* bv = (const float*)d_in[13];
    const float* Av = (const float*)d_in[14];
    const float* Bv = (const float*)d_in[15];

    bf16* weff = (bf16*)d_ws;                           // 3M   bf16 (6 MB)
    bf16* qkvh = weff + (size_t)3 * 1024 * 1024;        // 12M  bf16 (24 MB)
    bf16* xb   = qkvh + (size_t)3 * BTCH * SEQ * HID;   // 12M  bf16 (24 MB)
    bf16* vtb  = xb   + (size_t)3 * BTCH * SEQ * HID;   // 4M   bf16 (8 MB)

    weff_kernel<<<dim3(4096, 3), 256, 0, stream>>>(
        Wq, Aq, Bq, Wk, Ak, Bk, Wv, Av, Bv, weff);

    cast_kernel<<<dim3(2048, 3), 256, 0, stream>>>(q, k, v, xb);

    proj_kernel<<<dim3(HID / 128, BTCH * SEQ / 128, 3), 256, 0, stream>>>(
        xb, bq, bk, bv, weff, qkvh);

    vtrans_kernel<<<dim3(SEQ / 64, HID / 64, BTCH), 256, 0, stream>>>(
        qkvh + (size_t)2 * BTCH * SEQ * HID, vtb);

    attn_kernel<<<dim3(SEQ / 64, NH, BTCH), 256, 0, stream>>>(
        qkvh, vtb, ab, (float*)d_out);
}